// Round 8
// baseline (288.083 us; speedup 1.0000x reference)
//
#include <hip/hip_runtime.h>
#include <hip/hip_bf16.h>
#include <math.h>

#define N 8192
#define D 128
#define MARGIN 2e-5f

typedef __attribute__((ext_vector_type(8))) short short8;
typedef __attribute__((ext_vector_type(4))) float f32x4;
typedef unsigned long long u64;

__device__ __forceinline__ unsigned int ordered_u32(float f) {
    unsigned int b = __float_as_uint(f);
    return (b & 0x80000000u) ? ~b : (b | 0x80000000u);
}
__device__ __forceinline__ float ordered_inv(unsigned int u) {
    unsigned int b = (u & 0x80000000u) ? (u & 0x7FFFFFFFu) : ~u;
    return __uint_as_float(b);
}

// ---------------- prep: normalize, split to bf16 hi/lo, norms, init keys/counter
__global__ __launch_bounds__(256) void prep_kernel(const float* __restrict__ e,
                                                   __hip_bfloat16* __restrict__ hi,
                                                   __hip_bfloat16* __restrict__ lo,
                                                   float* __restrict__ nrm,
                                                   int* __restrict__ counter,
                                                   u64* __restrict__ neg_key) {
    if (blockIdx.x == 0 && threadIdx.x == 0) *counter = 0;
    int row  = blockIdx.x * 4 + (threadIdx.x >> 6);
    int lane = threadIdx.x & 63;
    if (lane == 0) neg_key[row] = ~0ull;
    float2 v = ((const float2*)(e + (size_t)row * D))[lane];
    float s = v.x * v.x + v.y * v.y;
    #pragma unroll
    for (int m = 1; m < 64; m <<= 1) s += __shfl_xor(s, m, 64);
    float nr = sqrtf(s);
    if (lane == 0) nrm[row] = nr;
    float rn = 1.0f / fmaxf(nr, 1e-8f);
    float e0 = v.x * rn, e1 = v.y * rn;
    __hip_bfloat16 h0 = __float2bfloat16(e0);
    __hip_bfloat16 h1 = __float2bfloat16(e1);
    __hip_bfloat16 l0 = __float2bfloat16(e0 - __bfloat162float(h0));
    __hip_bfloat16 l1 = __float2bfloat16(e1 - __bfloat162float(h1));
    ushort2 hh, ll;
    hh.x = *(unsigned short*)&h0; hh.y = *(unsigned short*)&h1;
    ll.x = *(unsigned short*)&l0; ll.y = *(unsigned short*)&l1;
    ((ushort2*)hi)[row * 64 + lane] = hh;
    ((ushort2*)lo)[row * 64 + lane] = ll;
}

// ---------------- mine: NEG ONLY. BM=64, A LDS-resident, B frags from L2.
// State per anchor: max dot (negv), 2nd max value (neg2), argmax idx (negi).
__global__ __launch_bounds__(256) void mine_kernel(
    const __hip_bfloat16* __restrict__ hi, const __hip_bfloat16* __restrict__ lo,
    const int* __restrict__ labels, int4* __restrict__ partials) {

    __shared__ short Ahi[64 * 128];
    __shared__ short Alo[64 * 128];
    __shared__ int   lab_sh[1024];

    const int tid = threadIdx.x;
    const int l = tid & 63;
    const int wid = tid >> 6;          // 0..3
    const int ihalf = wid >> 1, jhalf = wid & 1;
    const int i0 = blockIdx.x * 64;
    const int j0base = blockIdx.y * 1024;
    const int lq = l >> 4;             // 0..3
    const int ln = l & 15;             // 0..15

    // ---- stage A (hi+lo, 64 rows x K=128), swizzled: chunk c at slot c^(r&7)
    {
        const int r = tid >> 2;        // 0..63
        const int q = tid & 3;
        const short* srcH = (const short*)hi + (size_t)(i0 + r) * D;
        const short* srcL = (const short*)lo + (size_t)(i0 + r) * D;
        #pragma unroll
        for (int cc = 0; cc < 4; ++cc) {
            int c = q * 4 + cc;
            int slot = (c ^ (r & 7)) * 8;
            *(short8*)(Ahi + r * 128 + slot) = *(const short8*)(srcH + c * 8);
            *(short8*)(Alo + r * 128 + slot) = *(const short8*)(srcL + c * 8);
        }
    }
    ((int4*)lab_sh)[tid] = ((const int4*)(labels + j0base))[tid];
    __syncthreads();   // the only barrier

    // 8 anchors per lane: s = mt*4+rr -> row i0 + ihalf*32 + mt*16 + lq*4 + rr
    int ibase[2];
    #pragma unroll
    for (int mt = 0; mt < 2; ++mt) ibase[mt] = i0 + ihalf * 32 + mt * 16 + lq * 4;
    int li[8];
    #pragma unroll
    for (int s = 0; s < 8; ++s) li[s] = labels[ibase[s >> 2] + (s & 3)];

    float negv[8], neg2[8];
    int   negi[8];
    #pragma unroll
    for (int s = 0; s < 8; ++s) { negv[s] = -INFINITY; neg2[s] = -INFINITY; negi[s] = 0; }

    const short* __restrict__ hs = (const short*)hi;
    const short* __restrict__ ls = (const short*)lo;
    unsigned boff = (unsigned)(j0base + jhalf * 64 + ln) * D + lq * 8;

    for (int jt = 0; jt < 8; ++jt) {
        f32x4 acc[2][4];
        #pragma unroll
        for (int mt = 0; mt < 2; ++mt)
            #pragma unroll
            for (int nt = 0; nt < 4; ++nt) acc[mt][nt] = (f32x4){0.f, 0.f, 0.f, 0.f};

        #pragma unroll
        for (int kc = 0; kc < 4; ++kc) {
            short8 bh[4], bl[4];
            #pragma unroll
            for (int nt = 0; nt < 4; ++nt) {
                unsigned o = boff + (unsigned)(kc * 32 + nt * 16 * D);
                bh[nt] = *(const short8*)(hs + o);
                bl[nt] = *(const short8*)(ls + o);
            }
            #pragma unroll
            for (int mt = 0; mt < 2; ++mt) {
                int row = ihalf * 32 + mt * 16 + ln;
                int slot = (kc * 4 + lq) ^ (ln & 7);
                short8 ah = *(short8*)(Ahi + row * 128 + slot * 8);
                short8 al = *(short8*)(Alo + row * 128 + slot * 8);
                #pragma unroll
                for (int nt = 0; nt < 4; ++nt) {
                    acc[mt][nt] = __builtin_amdgcn_mfma_f32_16x16x32_bf16(ah, bh[nt], acc[mt][nt], 0, 0, 0);
                    acc[mt][nt] = __builtin_amdgcn_mfma_f32_16x16x32_bf16(ah, bl[nt], acc[mt][nt], 0, 0, 0);
                    acc[mt][nt] = __builtin_amdgcn_mfma_f32_16x16x32_bf16(al, bh[nt], acc[mt][nt], 0, 0, 0);
                }
            }
        }

        // ---- slim epilogue: streaming max + second-max, diff-label only
        const int jrow0 = j0base + jt * 128 + jhalf * 64 + ln;
        #pragma unroll
        for (int nt = 0; nt < 4; ++nt) {
            const int jv = jrow0 + nt * 16;
            const int lj = lab_sh[jv - j0base];
            #pragma unroll
            for (int mt = 0; mt < 2; ++mt) {
                #pragma unroll
                for (int rr = 0; rr < 4; ++rr) {
                    const int s = mt * 4 + rr;
                    float dneg = (lj == li[s]) ? -INFINITY : acc[mt][nt][rr];
                    bool u = dneg > negv[s];
                    neg2[s] = fmaxf(neg2[s], fminf(dneg, negv[s]));
                    negv[s] = fmaxf(negv[s], dneg);
                    negi[s] = u ? jv : negi[s];
                }
            }
        }
        boff += 128u * D;
    }

    // ---- butterfly over the 16 ln-lanes sharing each anchor group
    #pragma unroll
    for (int s = 0; s < 8; ++s) {
        float v = negv[s], v2 = neg2[s]; int ii = negi[s];
        #pragma unroll
        for (int off = 1; off < 16; off <<= 1) {
            float ov = __shfl_xor(v, off, 64); int oi = __shfl_xor(ii, off, 64);
            float o2 = __shfl_xor(v2, off, 64);
            v2 = fmaxf(fmaxf(v2, o2), fminf(v, ov));
            if (ov > v || (ov == v && oi < ii)) { v = ov; ii = oi; }
        }
        if (ln == s) {
            int arow = ibase[s >> 2] + (s & 3);
            partials[arow * 16 + blockIdx.y * 2 + jhalf] =
                make_int4(__float_as_int(v), ii, __float_as_int(v2), 0);
        }
    }
}

// ---------------- pos: one block per class, exact fp32 all-pairs within class
__global__ __launch_bounds__(256) void pos_kernel(
    const float* __restrict__ e, const int* __restrict__ labels,
    const float* __restrict__ nrm, float* __restrict__ out) {
    __shared__ float emb[96 * 129];
    __shared__ int   list_sh[96];
    __shared__ float rn_sh[96];
    __shared__ int   cnt_sh;
    const int tid = threadIdx.x;
    const int c = blockIdx.x;
    if (tid == 0) cnt_sh = 0;
    __syncthreads();
    for (int j = tid; j < N; j += 256) {
        if (labels[j] == c) {
            int p = atomicAdd(&cnt_sh, 1);
            if (p < 96) list_sh[p] = j;
        }
    }
    __syncthreads();
    const int m = min(cnt_sh, 96);
    if (m == 0) return;
    if (tid < m) rn_sh[tid] = 1.0f / fmaxf(nrm[list_sh[tid]], 1e-8f);
    __syncthreads();
    for (int x = tid; x < m * D; x += 256) {
        int idx = x >> 7, k = x & 127;
        emb[idx * 129 + k] = e[(size_t)list_sh[idx] * D + k] * rn_sh[idx];
    }
    __syncthreads();
    const int w = tid >> 6, l = tid & 63;
    for (int a = w; a < m; a += 4) {
        float bv = INFINITY; int bj = 0x7FFFFFFF;
        for (int b = l; b < m; b += 64) {
            if (b == a) continue;
            const float* ea = emb + a * 129;
            const float* eb = emb + b * 129;
            float s0 = 0.f, s1 = 0.f;
            #pragma unroll
            for (int k = 0; k < D; k += 2) {
                s0 = fmaf(ea[k], eb[k], s0);
                s1 = fmaf(ea[k + 1], eb[k + 1], s1);
            }
            float dot = s0 + s1;
            int j = list_sh[b];
            if (dot < bv || (dot == bv && j < bj)) { bv = dot; bj = j; }
        }
        #pragma unroll
        for (int off = 1; off < 64; off <<= 1) {
            float ov = __shfl_xor(bv, off, 64); int oj = __shfl_xor(bj, off, 64);
            if (ov < bv || (ov == bv && oj < bj)) { bv = ov; bj = oj; }
        }
        if (l == 0) {
            int row = list_sh[a];
            if (bv == INFINITY) { out[row * 3 + 1] = 0.0f; out[3 * N + row] = -INFINITY; }
            else { out[row * 3 + 1] = (float)bj; out[3 * N + row] = 1.0f - bv; }
        }
    }
}

// ---------------- combine: fold 16 neg partials/row, write, flag near-ties ----
__global__ __launch_bounds__(256) void combine_kernel(
    const int4* __restrict__ partials, float* __restrict__ out,
    int* __restrict__ list, int* __restrict__ counter) {
    int tid = threadIdx.x;
    int a = blockIdx.x * 64 + (tid >> 2);
    int q = tid & 3;
    float v = -INFINITY, v2 = -INFINITY; int ii = 0x7FFFFFFF;
    #pragma unroll
    for (int s = 0; s < 4; ++s) {
        int4 p = partials[a * 16 + q * 4 + s];
        float ov = __int_as_float(p.x);
        float o2 = __int_as_float(p.z);
        v2 = fmaxf(fmaxf(v2, o2), fminf(v, ov));
        if (ov > v || (ov == v && p.y < ii)) { v = ov; ii = p.y; }
    }
    #pragma unroll
    for (int off = 1; off < 4; off <<= 1) {
        float ov = __shfl_xor(v, off, 64); int oi = __shfl_xor(ii, off, 64);
        float o2 = __shfl_xor(v2, off, 64);
        v2 = fmaxf(fmaxf(v2, o2), fminf(v, ov));
        if (ov > v || (ov == v && oi < ii)) { v = ov; ii = oi; }
    }
    if (q == 0) {
        out[a * 3 + 0] = (float)a;
        out[a * 3 + 2] = (float)ii;
        out[4 * N + a] = 1.0f - v;
        if (v - v2 < MARGIN) {              // near-tie: exact recheck needed
            int k = atomicAdd(counter, 1);
            list[k] = a;
        }
    }
}

// ---------------- cleanup pass 1: exact fp32 neg rescan for flagged rows ------
__global__ __launch_bounds__(256) void cleanup1_kernel(
    const float* __restrict__ e, const int* __restrict__ labels,
    const float* __restrict__ nrm, const int* __restrict__ list,
    const int* __restrict__ counter, u64* __restrict__ neg_key) {
    __shared__ float enr[128];
    __shared__ u64 redn[4];
    const int tid = threadIdx.x;
    const int lane = tid & 63, w = tid >> 6;
    const int cnt = *counter;
    const int jb = blockIdx.y * 1024 + tid;

    for (int slot = blockIdx.x; slot < cnt; slot += gridDim.x) {
        __syncthreads();
        const int row = list[slot];
        if (tid < 128) enr[tid] = e[(size_t)row * D + tid] / fmaxf(nrm[row], 1e-8f);
        __syncthreads();
        const int lr = labels[row];

        u64 nk = ~0ull;
        #pragma unroll
        for (int jj = 0; jj < 4; ++jj) {
            const int j = jb + jj * 256;
            if (labels[j] == lr) continue;       // excludes self too
            const float4* ej = (const float4*)(e + (size_t)j * D);
            float s0 = 0.f, s1 = 0.f, s2 = 0.f, s3 = 0.f;
            #pragma unroll
            for (int cc = 0; cc < 32; cc += 4) {
                float4 v0 = ej[cc], v1 = ej[cc + 1], v2 = ej[cc + 2], v3 = ej[cc + 3];
                s0 = fmaf(v0.x, enr[4*cc   ], fmaf(v0.y, enr[4*cc+ 1], fmaf(v0.z, enr[4*cc+ 2], fmaf(v0.w, enr[4*cc+ 3], s0))));
                s1 = fmaf(v1.x, enr[4*cc+ 4], fmaf(v1.y, enr[4*cc+ 5], fmaf(v1.z, enr[4*cc+ 6], fmaf(v1.w, enr[4*cc+ 7], s1))));
                s2 = fmaf(v2.x, enr[4*cc+ 8], fmaf(v2.y, enr[4*cc+ 9], fmaf(v2.z, enr[4*cc+10], fmaf(v2.w, enr[4*cc+11], s2))));
                s3 = fmaf(v3.x, enr[4*cc+12], fmaf(v3.y, enr[4*cc+13], fmaf(v3.z, enr[4*cc+14], fmaf(v3.w, enr[4*cc+15], s3))));
            }
            float dd = 1.0f - ((s0 + s1) + (s2 + s3)) / fmaxf(nrm[j], 1e-8f);
            u64 k = ((u64)ordered_u32(dd) << 32) | (unsigned int)j;
            if (k < nk) nk = k;
        }
        #pragma unroll
        for (int off = 1; off < 64; off <<= 1) {
            u64 on = __shfl_xor(nk, off, 64); if (on < nk) nk = on;
        }
        if (lane == 0) redn[w] = nk;
        __syncthreads();
        if (tid == 0) {
            #pragma unroll
            for (int q = 1; q < 4; ++q) if (redn[q] < nk) nk = redn[q];
            if (nk != ~0ull) atomicMin(&neg_key[row], nk);
        }
    }
}

// ---------------- cleanup pass 2: decode keys, overwrite flagged rows ----------
__global__ __launch_bounds__(256) void cleanup2_kernel(
    const u64* __restrict__ neg_key, const int* __restrict__ list,
    const int* __restrict__ counter, float* __restrict__ out) {
    int idx = blockIdx.x * 256 + threadIdx.x;
    int cnt = *counter;
    if (idx >= cnt) return;
    int row = list[idx];
    u64 nk = neg_key[row];
    if (nk != ~0ull) {
        unsigned int u = (unsigned int)(nk >> 32);
        out[row * 3 + 2] = (float)(unsigned int)(nk & 0xFFFFFFFFu);
        out[4 * N + row] = ordered_inv(u);
    }
}

extern "C" void kernel_launch(void* const* d_in, const int* in_sizes, int n_in,
                              void* d_out, int out_size, void* d_ws, size_t ws_size,
                              hipStream_t stream) {
    const float* e      = (const float*)d_in[0];
    const int*   labels = (const int*)d_in[1];
    float* out = (float*)d_out;

    char* wsb = (char*)d_ws;
    __hip_bfloat16* hi = (__hip_bfloat16*)wsb;                          // 2 MB
    __hip_bfloat16* lo = hi + (size_t)N * D;                            // 2 MB
    float* nrm   = (float*)(wsb + 4u * 1024 * 1024);                    // 32 KB
    int4*  parts = (int4*)(wsb + 4u * 1024 * 1024 + 65536);             // 2 MB
    int*   list  = (int*)(wsb + 7u * 1024 * 1024);                      // 32 KB
    int*   cnt   = (int*)(wsb + 7u * 1024 * 1024 + 65536);              // 4 B
    u64*   nkey  = (u64*)(wsb + 7u * 1024 * 1024 + 131072);             // 64 KB

    prep_kernel<<<N / 4, 256, 0, stream>>>(e, hi, lo, nrm, cnt, nkey);
    mine_kernel<<<dim3(N / 64, 8), 256, 0, stream>>>(hi, lo, labels, parts);
    pos_kernel<<<256, 256, 0, stream>>>(e, labels, nrm, out);
    combine_kernel<<<N / 64, 256, 0, stream>>>(parts, out, list, cnt);
    cleanup1_kernel<<<dim3(256, 8), 256, 0, stream>>>(e, labels, nrm, list, cnt, nkey);
    cleanup2_kernel<<<32, 256, 0, stream>>>(nkey, list, cnt, out);
}